// Round 9
// baseline (239.066 us; speedup 1.0000x reference)
//
#include <hip/hip_runtime.h>
#include <hip/hip_bf16.h>
#include <math.h>

#define D_DIM 1024
#define NROWS 32768      // 4*16*512
#define NE_ROWS 1024     // 4*16*16 unique engram rows
#define A1_ROWS 1536     // engram rows + 512 pos rows
#define NT2 32           // GEMM2 K-steps of 32

typedef __attribute__((ext_vector_type(8))) short bf16x8;
typedef __attribute__((ext_vector_type(4))) float f32x4;

static __device__ __forceinline__ ushort f2bf(float f) {
  union { float f; unsigned u; } un; un.f = f;
  unsigned u = un.u;
  unsigned r = u + 0x7fffu + ((u >> 16) & 1u);
  return (ushort)(r >> 16);
}
static __device__ __forceinline__ float bf2f(ushort h) {
  union { unsigned u; float f; } un; un.u = ((unsigned)h) << 16;
  return un.f;
}
static __device__ __forceinline__ float gelu_exact(float v) {
  return 0.5f * v * (1.0f + erff(v * 0.70710678118654752f));
}

// ---- fused cast fp32 -> bf16 of w1|w2|eng|pos into contiguous ws region ----
__global__ void cast_all_kernel(const float* __restrict__ w1, const float* __restrict__ w2,
                                const float* __restrict__ eng, const float* __restrict__ pos,
                                ushort* __restrict__ dst) {
  int i = blockIdx.x * blockDim.x + threadIdx.x;   // float4 units, 0..917503
  float4 v;
  if (i < 262144) v = ((const float4*)w1)[i];
  else if (i < 524288) v = ((const float4*)w2)[i - 262144];
  else if (i < 786432) v = ((const float4*)eng)[i - 524288];
  else v = ((const float4*)pos)[i - 786432];
  ushort4 o;
  o.x = f2bf(v.x); o.y = f2bf(v.y); o.z = f2bf(v.z); o.w = f2bf(v.w);
  ((ushort4*)dst)[i] = o;
}

// ---- 128x128 bf16 MFMA GEMM + row-ranged bias (b1 folded into pos rows) ----
__global__ __launch_bounds__(256) void gemm_bt(const ushort* __restrict__ A,
                                               const ushort* __restrict__ B,
                                               float* __restrict__ C,
                                               int M, int N, int K,
                                               const float* __restrict__ bias,
                                               int biasRow0) {
  __shared__ ushort sA[128 * 64];
  __shared__ ushort sB[128 * 64];

  int nwg = gridDim.x;
  int bid = blockIdx.x;
  if ((nwg & 7) == 0) {
    int cpx = nwg >> 3;
    bid = (bid & 7) * cpx + (bid >> 3);
  }
  int ntn = N >> 7;
  int mt = bid / ntn, nt = bid % ntn;
  int brow = mt << 7, bcol = nt << 7;

  int tid = threadIdx.x;
  int wv = tid >> 6, lane = tid & 63;
  int wm = (wv >> 1) << 6, wn = (wv & 1) << 6;
  int lr = lane & 15, lk = lane >> 4;
  int srow = lane >> 3;
  int scolsw = (((lane & 7) ^ ((lane >> 3) & 7)) << 3);

  f32x4 acc[4][4];
#pragma unroll
  for (int m = 0; m < 4; ++m)
#pragma unroll
    for (int n = 0; n < 4; ++n) acc[m][n] = (f32x4){0.f, 0.f, 0.f, 0.f};

  for (int k0 = 0; k0 < K; k0 += 64) {
    __syncthreads();
#pragma unroll
    for (int j = 0; j < 4; ++j) {
      int c = (wv << 2) + j;
      int row = (c << 3) + srow;
      const ushort* gA = A + (brow + row) * K + k0 + scolsw;
      const ushort* gB = B + (bcol + row) * K + k0 + scolsw;
      __builtin_amdgcn_global_load_lds(
          (const __attribute__((address_space(1))) unsigned int*)gA,
          (__attribute__((address_space(3))) unsigned int*)&sA[c << 9], 16, 0, 0);
      __builtin_amdgcn_global_load_lds(
          (const __attribute__((address_space(1))) unsigned int*)gB,
          (__attribute__((address_space(3))) unsigned int*)&sB[c << 9], 16, 0, 0);
    }
    __syncthreads();
#pragma unroll
    for (int kk = 0; kk < 2; ++kk) {
      int rdoff = (((kk << 2) | lk) ^ (lr & 7)) << 3;
      bf16x8 af[4], bfr[4];
#pragma unroll
      for (int m = 0; m < 4; ++m)
        af[m] = *(const bf16x8*)&sA[(wm + (m << 4) + lr) * 64 + rdoff];
#pragma unroll
      for (int n = 0; n < 4; ++n)
        bfr[n] = *(const bf16x8*)&sB[(wn + (n << 4) + lr) * 64 + rdoff];
#pragma unroll
      for (int m = 0; m < 4; ++m)
#pragma unroll
        for (int n = 0; n < 4; ++n)
          acc[m][n] = __builtin_amdgcn_mfma_f32_16x16x32_bf16(af[m], bfr[n], acc[m][n], 0, 0, 0);
    }
  }

#pragma unroll
  for (int m = 0; m < 4; ++m)
#pragma unroll
    for (int n = 0; n < 4; ++n)
#pragma unroll
      for (int i = 0; i < 4; ++i) {
        int row = brow + wm + (m << 4) + (lk << 2) + i;
        int col = bcol + wn + (n << 4) + lr;
        float v = acc[m][n][i];
        if (row >= biasRow0) v += bias[col];
        C[(long)row * N + col] = v;
      }
}

// ---- h = gelu_exact(xw1_e[er] + xw1_p[w]) -> bf16 (b1 already in pos rows) ----
__global__ __launch_bounds__(256) void gelu_kernel(const float* __restrict__ xw1,
                                                   ushort* __restrict__ h) {
  int r = blockIdx.x;
  int t = threadIdx.x;
  int bn = r >> 9;
  int w = r & 511;
  int er = bn * 16 + (w >> 5);
  float4 e = ((const float4*)(xw1 + er * D_DIM))[t];
  float4 p = ((const float4*)(xw1 + (NE_ROWS + w) * D_DIM))[t];
  ushort4 o;
  o.x = f2bf(gelu_exact(e.x + p.x));
  o.y = f2bf(gelu_exact(e.y + p.y));
  o.z = f2bf(gelu_exact(e.z + p.z));
  o.w = f2bf(gelu_exact(e.w + p.w));
  ((ushort4*)(h + (long)r * D_DIM))[t] = o;
}

// ---- GEMM2: 128x128 tile, 4 waves; A via LDS (16 KiB), B direct L2->VGPR ----
// Y(bf16) = h @ W2^T, interleaved: ushort at Y + row*2048 + col.
// B(t+1) issued at TOP of step t (full step to land); ledger: enter={A(t+1)x2},
// +B(t+1)x4, +A(t+2)x2 after BAR, vmcnt(2) certifies A(t+1)+B(t+1).
// A swizzle: phys 16B-slot s at row r holds logical s^((r>>1)&3).
__global__ __launch_bounds__(256, 3) void gemm2_128(const ushort* __restrict__ A,
                                                    const ushort* __restrict__ B,
                                                    ushort* __restrict__ Y) {
  __shared__ ushort sA[2][4096];
  const int K = 1024;

  // XCD map: all 8 N-tiles of an M-panel stay on one XCD (A+B L2-reuse)
  int bid = blockIdx.x;                // 2048 blocks
  int x = bid & 7, jj = bid >> 3;
  int mt = (x << 5) + (jj >> 3);       // 0..255
  int nt = jj & 7;                     // 0..7
  long brow = (long)mt << 7;
  int bcol = nt << 7;

  int tid = threadIdx.x;
  int wv = tid >> 6, l = tid & 63;
  int wr = wv >> 1, wc = wv & 1;       // 2x2 wave grid; wave tile 64x64
  int lr = l & 15, lk = l >> 4;

  // A staging: instr j2 covers rows [j2*64, j2*64+64): row = j2*64 + wv*16 + (l>>2)
  int srow0 = (wv << 4) + (l >> 2);
  int slog = (((l & 3) ^ ((l >> 3) & 3)) << 3);
  const ushort* aS = A + (brow + srow0) * (long)K + slog;

  // A fragment read offsets (swizzled)
  int rdswz = (lk ^ ((lr >> 1) & 3)) << 3;
  int aO = (((wr << 6) + lr) << 5) + rdswz;   // + m<<9

  // B fragment base: lane reads W2[bcol + wc*64 + n*16 + lr][k0 + lk*8 .. +8]
  const ushort* bF = B + ((size_t)(bcol + (wc << 6) + lr) << 10) + (lk << 3);

  f32x4 acc[4][4];
#pragma unroll
  for (int m = 0; m < 4; ++m)
#pragma unroll
    for (int n = 0; n < 4; ++n) acc[m][n] = (f32x4){0.f, 0.f, 0.f, 0.f};

#define STG(kt) do {                                                                 \
    int p_ = (kt) & 1; int ko_ = (kt) << 5;                                          \
    _Pragma("unroll")                                                                \
    for (int j2 = 0; j2 < 2; ++j2) {                                                 \
      __builtin_amdgcn_global_load_lds(                                              \
        (const __attribute__((address_space(1))) unsigned int*)(aS + ko_ + (long)(j2 << 6) * K), \
        (__attribute__((address_space(3))) unsigned int*)&sA[p_][(j2 << 11) + (wv << 9)], 16, 0, 0); \
    } } while (0)

#define LDB(BUF, kt) do {                                                            \
    _Pragma("unroll")                                                                \
    for (int n = 0; n < 4; ++n)                                                      \
      BUF[n] = *(const bf16x8*)(bF + ((size_t)n << 14) + ((kt) << 5));               \
    __builtin_amdgcn_sched_barrier(0);                                               \
  } while (0)

#define BAR asm volatile("s_barrier" ::: "memory")

  bf16x8 bA[4], bB[4];

  // prologue: FIFO = A0(2), B0(4), A1(2); vmcnt(2) certifies A0+B0, leaves A1.
  STG(0);
  __builtin_amdgcn_sched_barrier(0);
  LDB(bA, 0);
  STG(1);
  asm volatile("s_waitcnt vmcnt(2)" ::: "memory");
  BAR;

  // STEP(t, BU, BL): uses BU=B(t), prefetches B(t+1) into BL at top of step.
#define STEP(t, BU, BL) do {                                                         \
    if ((t) + 1 < NT2) LDB(BL, (t) + 1);        /* issue early: full step to land */ \
    bf16x8 af[4];                                                                    \
    _Pragma("unroll")                                                                \
    for (int m = 0; m < 4; ++m) af[m] = *(const bf16x8*)&sA[(t) & 1][aO + (m << 9)]; \
    __builtin_amdgcn_s_setprio(1);                                                   \
    _Pragma("unroll")                                                                \
    for (int m = 0; m < 4; ++m)                                                      \
      _Pragma("unroll")                                                              \
      for (int n = 0; n < 4; ++n)                                                    \
        acc[m][n] = __builtin_amdgcn_mfma_f32_16x16x32_bf16(af[m], BU[n], acc[m][n], 0, 0, 0); \
    __builtin_amdgcn_s_setprio(0);                                                   \
    if ((t) < NT2 - 1) {                                                             \
      BAR;                                       /* all waves done reading sA[t&1] */ \
      if ((t) + 2 < NT2) {                                                           \
        STG((t) + 2);                                                                \
        asm volatile("s_waitcnt vmcnt(2)" ::: "memory");  /* certify A(t+1)+B(t+1) */ \
      } else {                                                                       \
        asm volatile("s_waitcnt vmcnt(0)" ::: "memory");  /* tail drain */           \
      }                                                                              \
      BAR;                                                                           \
    }                                                                                \
  } while (0)

  for (int t = 0; t < NT2; t += 2) {
    STEP(t, bA, bB);
    STEP(t + 1, bB, bA);
  }
#undef STEP
#undef STG
#undef LDB
#undef BAR

  // epilogue: bf16 y into interleaved out rows (first 1024 ushorts of 4KB row)
#pragma unroll
  for (int m = 0; m < 4; ++m)
#pragma unroll
    for (int n = 0; n < 4; ++n) {
      int col = bcol + (wc << 6) + (n << 4) + lr;
#pragma unroll
      for (int i = 0; i < 4; ++i) {
        long row = brow + (wr << 6) + (m << 4) + (lk << 2) + i;
        Y[(row << 11) + col] = f2bf(acc[m][n][i]);
      }
    }
}

// ---- out = LayerNorm((eng+pos) + y + b2); y read bf16-interleaved from out ----
__global__ __launch_bounds__(256) void ln_kernel(const float* __restrict__ eng,
                                                 const float* __restrict__ pos,
                                                 const float* __restrict__ b2,
                                                 const float* __restrict__ gamma,
                                                 const float* __restrict__ beta,
                                                 float* __restrict__ out) {
  __shared__ float red[8];
  int r = blockIdx.x;
  int t = threadIdx.x;
  int bn = r >> 9, w = r & 511;
  int er = bn * 16 + (w >> 5);
  float4 xe = ((const float4*)(eng + er * D_DIM))[t];
  float4 xp = ((const float4*)(pos + w * D_DIM))[t];
  ushort4 yv = ((const ushort4*)((const ushort*)out + ((size_t)r << 11)))[t];
  float4 bb = ((const float4*)b2)[t];
  float v0 = xe.x + xp.x + bf2f(yv.x) + bb.x;
  float v1 = xe.y + xp.y + bf2f(yv.y) + bb.y;
  float v2 = xe.z + xp.z + bf2f(yv.z) + bb.z;
  float v3 = xe.w + xp.w + bf2f(yv.w) + bb.w;
  float s  = v0 + v1 + v2 + v3;
  float sq = v0 * v0 + v1 * v1 + v2 * v2 + v3 * v3;
  int lane = t & 63, wv = t >> 6;
#pragma unroll
  for (int off = 32; off > 0; off >>= 1) {
    s  += __shfl_down(s, off);
    sq += __shfl_down(sq, off);
  }
  if (lane == 0) { red[wv] = s; red[4 + wv] = sq; }
  __syncthreads();
  float S  = red[0] + red[1] + red[2] + red[3];
  float SQ = red[4] + red[5] + red[6] + red[7];
  float mu = S * (1.0f / 1024.0f);
  float var = SQ * (1.0f / 1024.0f) - mu * mu;
  float rs = rsqrtf(var + 1e-5f);
  float4 g = ((const float4*)gamma)[t];
  float4 bt = ((const float4*)beta)[t];
  float4 o;
  o.x = (v0 - mu) * rs * g.x + bt.x;
  o.y = (v1 - mu) * rs * g.y + bt.y;
  o.z = (v2 - mu) * rs * g.z + bt.z;
  o.w = (v3 - mu) * rs * g.w + bt.w;
  ((float4*)(out + ((size_t)r << 10)))[t] = o;
}

extern "C" void kernel_launch(void* const* d_in, const int* in_sizes, int n_in,
                              void* d_out, int out_size, void* d_ws, size_t ws_size,
                              hipStream_t stream) {
  const float* eng   = (const float*)d_in[0];
  const float* pos   = (const float*)d_in[1];
  const float* w1    = (const float*)d_in[2];
  const float* b1    = (const float*)d_in[3];
  const float* w2    = (const float*)d_in[4];
  const float* b2    = (const float*)d_in[5];
  const float* gamma = (const float*)d_in[6];
  const float* beta  = (const float*)d_in[7];
  float* out = (float*)d_out;

  char* ws = (char*)d_ws;
  ushort* w1b = (ushort*)(ws);                     // 2 MiB  (cast block start)
  ushort* w2b = (ushort*)(ws + (2u << 20));        // 2 MiB
  ushort* a1b = (ushort*)(ws + (4u << 20));        // 3 MiB: [eng;pos] bf16
  float*  xw1 = (float*)(ws + (7u << 20));         // 6 MiB: 1536x1024 f32
  ushort* hb  = (ushort*)(ws + (13u << 20));       // 64 MiB: 32768x1024 bf16

  // 1) fused casts to bf16 (w1|w2|eng|pos contiguous at ws base)
  cast_all_kernel<<<3584, 256, 0, stream>>>(w1, w2, eng, pos, w1b);

  // 2) GEMM1: xw1 = [engrams; pos] @ W1^T, +b1 folded into pos-rows
  gemm_bt<<<(A1_ROWS / 128) * (D_DIM / 128), 256, 0, stream>>>(a1b, w1b, xw1,
                                                               A1_ROWS, D_DIM, D_DIM,
                                                               b1, NE_ROWS);

  // 3) h = gelu(xw1_e + xw1_p) -> bf16   (b1 already folded)
  gelu_kernel<<<NROWS, 256, 0, stream>>>(xw1, hb);

  // 4) GEMM2: y(bf16) = h @ W2^T; A via LDS, B direct from L2 (early-issue)
  gemm2_128<<<2048, 256, 0, stream>>>(hb, w2b, (ushort*)out);

  // 5) LayerNorm epilogue (exact fp32 residual recompute)
  ln_kernel<<<NROWS, 256, 0, stream>>>(eng, pos, b2, gamma, beta, out);
}

// Round 10
// 177.960 us; speedup vs baseline: 1.3434x; 1.3434x over previous
//
#include <hip/hip_runtime.h>
#include <hip/hip_bf16.h>
#include <math.h>

#define D_DIM 1024
#define NROWS 32768      // 4*16*512
#define NE_ROWS 1024     // 4*16*16 unique engram rows
#define A1_ROWS 1536     // engram rows + 512 pos rows
#define NT2 32           // GEMM2 K-steps of 32

typedef __attribute__((ext_vector_type(8))) short bf16x8;
typedef __attribute__((ext_vector_type(4))) float f32x4;

static __device__ __forceinline__ ushort f2bf(float f) {
  union { float f; unsigned u; } un; un.f = f;
  unsigned u = un.u;
  unsigned r = u + 0x7fffu + ((u >> 16) & 1u);
  return (ushort)(r >> 16);
}
static __device__ __forceinline__ float bf2f(ushort h) {
  union { unsigned u; float f; } un; un.u = ((unsigned)h) << 16;
  return un.f;
}
static __device__ __forceinline__ float gelu_exact(float v) {
  return 0.5f * v * (1.0f + erff(v * 0.70710678118654752f));
}

// ---- fused cast fp32 -> bf16 of w1|w2|eng|pos into contiguous ws region ----
__global__ void cast_all_kernel(const float* __restrict__ w1, const float* __restrict__ w2,
                                const float* __restrict__ eng, const float* __restrict__ pos,
                                ushort* __restrict__ dst) {
  int i = blockIdx.x * blockDim.x + threadIdx.x;   // float4 units, 0..917503
  float4 v;
  if (i < 262144) v = ((const float4*)w1)[i];
  else if (i < 524288) v = ((const float4*)w2)[i - 262144];
  else if (i < 786432) v = ((const float4*)eng)[i - 524288];
  else v = ((const float4*)pos)[i - 786432];
  ushort4 o;
  o.x = f2bf(v.x); o.y = f2bf(v.y); o.z = f2bf(v.z); o.w = f2bf(v.w);
  ((ushort4*)dst)[i] = o;
}

// ---- 128x128 bf16 MFMA GEMM + row-ranged bias (b1 folded into pos rows) ----
__global__ __launch_bounds__(256) void gemm_bt(const ushort* __restrict__ A,
                                               const ushort* __restrict__ B,
                                               float* __restrict__ C,
                                               int M, int N, int K,
                                               const float* __restrict__ bias,
                                               int biasRow0) {
  __shared__ ushort sA[128 * 64];
  __shared__ ushort sB[128 * 64];

  int nwg = gridDim.x;
  int bid = blockIdx.x;
  if ((nwg & 7) == 0) {
    int cpx = nwg >> 3;
    bid = (bid & 7) * cpx + (bid >> 3);
  }
  int ntn = N >> 7;
  int mt = bid / ntn, nt = bid % ntn;
  int brow = mt << 7, bcol = nt << 7;

  int tid = threadIdx.x;
  int wv = tid >> 6, lane = tid & 63;
  int wm = (wv >> 1) << 6, wn = (wv & 1) << 6;
  int lr = lane & 15, lk = lane >> 4;
  int srow = lane >> 3;
  int scolsw = (((lane & 7) ^ ((lane >> 3) & 7)) << 3);

  f32x4 acc[4][4];
#pragma unroll
  for (int m = 0; m < 4; ++m)
#pragma unroll
    for (int n = 0; n < 4; ++n) acc[m][n] = (f32x4){0.f, 0.f, 0.f, 0.f};

  for (int k0 = 0; k0 < K; k0 += 64) {
    __syncthreads();
#pragma unroll
    for (int j = 0; j < 4; ++j) {
      int c = (wv << 2) + j;
      int row = (c << 3) + srow;
      const ushort* gA = A + (brow + row) * K + k0 + scolsw;
      const ushort* gB = B + (bcol + row) * K + k0 + scolsw;
      __builtin_amdgcn_global_load_lds(
          (const __attribute__((address_space(1))) unsigned int*)gA,
          (__attribute__((address_space(3))) unsigned int*)&sA[c << 9], 16, 0, 0);
      __builtin_amdgcn_global_load_lds(
          (const __attribute__((address_space(1))) unsigned int*)gB,
          (__attribute__((address_space(3))) unsigned int*)&sB[c << 9], 16, 0, 0);
    }
    __syncthreads();
#pragma unroll
    for (int kk = 0; kk < 2; ++kk) {
      int rdoff = (((kk << 2) | lk) ^ (lr & 7)) << 3;
      bf16x8 af[4], bfr[4];
#pragma unroll
      for (int m = 0; m < 4; ++m)
        af[m] = *(const bf16x8*)&sA[(wm + (m << 4) + lr) * 64 + rdoff];
#pragma unroll
      for (int n = 0; n < 4; ++n)
        bfr[n] = *(const bf16x8*)&sB[(wn + (n << 4) + lr) * 64 + rdoff];
#pragma unroll
      for (int m = 0; m < 4; ++m)
#pragma unroll
        for (int n = 0; n < 4; ++n)
          acc[m][n] = __builtin_amdgcn_mfma_f32_16x16x32_bf16(af[m], bfr[n], acc[m][n], 0, 0, 0);
    }
  }

#pragma unroll
  for (int m = 0; m < 4; ++m)
#pragma unroll
    for (int n = 0; n < 4; ++n)
#pragma unroll
      for (int i = 0; i < 4; ++i) {
        int row = brow + wm + (m << 4) + (lk << 2) + i;
        int col = bcol + wn + (n << 4) + lr;
        float v = acc[m][n][i];
        if (row >= biasRow0) v += bias[col];
        C[(long)row * N + col] = v;
      }
}

// ---- h = gelu_exact(xw1_e[er] + xw1_p[w]) -> bf16 (b1 already in pos rows) ----
__global__ __launch_bounds__(256) void gelu_kernel(const float* __restrict__ xw1,
                                                   ushort* __restrict__ h) {
  int r = blockIdx.x;
  int t = threadIdx.x;
  int bn = r >> 9;
  int w = r & 511;
  int er = bn * 16 + (w >> 5);
  float4 e = ((const float4*)(xw1 + er * D_DIM))[t];
  float4 p = ((const float4*)(xw1 + (NE_ROWS + w) * D_DIM))[t];
  ushort4 o;
  o.x = f2bf(gelu_exact(e.x + p.x));
  o.y = f2bf(gelu_exact(e.y + p.y));
  o.z = f2bf(gelu_exact(e.z + p.z));
  o.w = f2bf(gelu_exact(e.w + p.w));
  ((ushort4*)(h + (long)r * D_DIM))[t] = o;
}

// ---- GEMM2: 128x128 tile, 4 waves, BK=32; 4-buffer ring, 1 barrier/step ----
// Y(bf16) = h @ W2^T, interleaved: ushort at Y + row*2048 + col.
// Step t: reads buf[t&3]; STG(t+3)->buf[(t+3)&3]; MFMA; vmcnt(8); BAR.
// Depth-3 prefetch (~3 steps of flight for HBM latency), 32 barriers total.
// Safety: buf[(t+3)&3] was consumed before end-of-(t-1) barrier (reads retired
// pre-MFMA via lgkmcnt); in-step reads (buf[t&3]) and writes target distinct bufs.
// Swizzle: phys 16B-slot s at row r holds logical s^((r>>1)&3).
__global__ __launch_bounds__(256, 2) void gemm2_128(const ushort* __restrict__ A,
                                                    const ushort* __restrict__ B,
                                                    ushort* __restrict__ Y) {
  __shared__ ushort sA[4][4096];
  __shared__ ushort sB[4][4096];
  const int K = 1024;

  // XCD map: all 8 N-tiles of an M-panel stay on one XCD (A+B L2-reuse)
  int bid = blockIdx.x;                // 2048 blocks
  int x = bid & 7, jj = bid >> 3;
  int mt = (x << 5) + (jj >> 3);       // 0..255
  int nt = jj & 7;                     // 0..7
  long brow = (long)mt << 7;
  int bcol = nt << 7;

  int tid = threadIdx.x;
  int wv = tid >> 6, l = tid & 63;
  int wr = wv >> 1, wc = wv & 1;       // 2x2 wave grid; wave tile 64x64
  int lr = l & 15, lk = l >> 4;

  // staging: instr j2 covers rows [j2*64, j2*64+64): row = j2*64 + wv*16 + (l>>2)
  // phys slot l&3; pre-swizzled logical slot (l&3)^((l>>3)&3)  [= (row>>1)&3]
  int srow0 = (wv << 4) + (l >> 2);
  int slog = (((l & 3) ^ ((l >> 3) & 3)) << 3);
  const ushort* aS = A + (brow + srow0) * (long)K + slog;
  const ushort* bS = B + (size_t)(bcol + srow0) * K + slog;

  // fragment read offsets (swizzled)
  int rdswz = (lk ^ ((lr >> 1) & 3)) << 3;
  int aO = (((wr << 6) + lr) << 5) + rdswz;   // + m<<9
  int bO = (((wc << 6) + lr) << 5) + rdswz;   // + n<<9

  f32x4 acc[4][4];
#pragma unroll
  for (int m = 0; m < 4; ++m)
#pragma unroll
    for (int n = 0; n < 4; ++n) acc[m][n] = (f32x4){0.f, 0.f, 0.f, 0.f};

#define STG(kt) do {                                                                 \
    int p_ = (kt) & 3; int ko_ = (kt) << 5;                                          \
    _Pragma("unroll")                                                                \
    for (int j2 = 0; j2 < 2; ++j2) {                                                 \
      __builtin_amdgcn_global_load_lds(                                              \
        (const __attribute__((address_space(1))) unsigned int*)(aS + ko_ + (long)(j2 << 6) * K), \
        (__attribute__((address_space(3))) unsigned int*)&sA[p_][(j2 << 11) + (wv << 9)], 16, 0, 0); \
      __builtin_amdgcn_global_load_lds(                                              \
        (const __attribute__((address_space(1))) unsigned int*)(bS + ko_ + (long)(j2 << 6) * K), \
        (__attribute__((address_space(3))) unsigned int*)&sB[p_][(j2 << 11) + (wv << 9)], 16, 0, 0); \
    } } while (0)

#define BAR asm volatile("s_barrier" ::: "memory")

  // prologue: tiles 0,1,2 in flight (12 loads); certify tile 0 (vmcnt 12->8)
  STG(0); STG(1); STG(2);
  asm volatile("s_waitcnt vmcnt(8)" ::: "memory");
  BAR;

#pragma unroll
  for (int t = 0; t < NT2; ++t) {
    bf16x8 af[4], bf[4];
#pragma unroll
    for (int n = 0; n < 4; ++n) bf[n] = *(const bf16x8*)&sB[t & 3][bO + (n << 9)];
#pragma unroll
    for (int m = 0; m < 4; ++m) af[m] = *(const bf16x8*)&sA[t & 3][aO + (m << 9)];
    if (t + 3 < NT2) STG(t + 3);      // issue early; lands by end of step t+2
    __builtin_amdgcn_s_setprio(1);
#pragma unroll
    for (int m = 0; m < 4; ++m)
#pragma unroll
      for (int n = 0; n < 4; ++n)
        acc[m][n] = __builtin_amdgcn_mfma_f32_16x16x32_bf16(af[m], bf[n], acc[m][n], 0, 0, 0);
    __builtin_amdgcn_s_setprio(0);
    if (t == NT2 - 1) break;
    // certify buf[(t+1)&3]: steady outstanding {t+1,t+2,t+3}=12 -> keep 8
    if (t + 3 < NT2)       asm volatile("s_waitcnt vmcnt(8)" ::: "memory");
    else if (t == NT2 - 3) asm volatile("s_waitcnt vmcnt(4)" ::: "memory");
    else                   asm volatile("s_waitcnt vmcnt(0)" ::: "memory");
    BAR;   // all waves: buf[t&3] reads retired (pre-MFMA) + buf[(t+1)&3] certified
  }
#undef STG
#undef BAR

  // epilogue: bf16 y into interleaved out rows (first 1024 ushorts of 4KB row)
#pragma unroll
  for (int m = 0; m < 4; ++m)
#pragma unroll
    for (int n = 0; n < 4; ++n) {
      int col = bcol + (wc << 6) + (n << 4) + lr;
#pragma unroll
      for (int i = 0; i < 4; ++i) {
        long row = brow + (wr << 6) + (m << 4) + (lk << 2) + i;
        Y[(row << 11) + col] = f2bf(acc[m][n][i]);
      }
    }
}

// ---- out = LayerNorm((eng+pos) + y + b2); y read bf16-interleaved from out ----
__global__ __launch_bounds__(256) void ln_kernel(const float* __restrict__ eng,
                                                 const float* __restrict__ pos,
                                                 const float* __restrict__ b2,
                                                 const float* __restrict__ gamma,
                                                 const float* __restrict__ beta,
                                                 float* __restrict__ out) {
  __shared__ float red[8];
  int r = blockIdx.x;
  int t = threadIdx.x;
  int bn = r >> 9, w = r & 511;
  int er = bn * 16 + (w >> 5);
  float4 xe = ((const float4*)(eng + er * D_DIM))[t];
  float4 xp = ((const float4*)(pos + w * D_DIM))[t];
  ushort4 yv = ((const ushort4*)((const ushort*)out + ((size_t)r << 11)))[t];
  float4 bb = ((const float4*)b2)[t];
  float v0 = xe.x + xp.x + bf2f(yv.x) + bb.x;
  float v1 = xe.y + xp.y + bf2f(yv.y) + bb.y;
  float v2 = xe.z + xp.z + bf2f(yv.z) + bb.z;
  float v3 = xe.w + xp.w + bf2f(yv.w) + bb.w;
  float s  = v0 + v1 + v2 + v3;
  float sq = v0 * v0 + v1 * v1 + v2 * v2 + v3 * v3;
  int lane = t & 63, wv = t >> 6;
#pragma unroll
  for (int off = 32; off > 0; off >>= 1) {
    s  += __shfl_down(s, off);
    sq += __shfl_down(sq, off);
  }
  if (lane == 0) { red[wv] = s; red[4 + wv] = sq; }
  __syncthreads();
  float S  = red[0] + red[1] + red[2] + red[3];
  float SQ = red[4] + red[5] + red[6] + red[7];
  float mu = S * (1.0f / 1024.0f);
  float var = SQ * (1.0f / 1024.0f) - mu * mu;
  float rs = rsqrtf(var + 1e-5f);
  float4 g = ((const float4*)gamma)[t];
  float4 bt = ((const float4*)beta)[t];
  float4 o;
  o.x = (v0 - mu) * rs * g.x + bt.x;
  o.y = (v1 - mu) * rs * g.y + bt.y;
  o.z = (v2 - mu) * rs * g.z + bt.z;
  o.w = (v3 - mu) * rs * g.w + bt.w;
  ((float4*)(out + ((size_t)r << 10)))[t] = o;
}

extern "C" void kernel_launch(void* const* d_in, const int* in_sizes, int n_in,
                              void* d_out, int out_size, void* d_ws, size_t ws_size,
                              hipStream_t stream) {
  const float* eng   = (const float*)d_in[0];
  const float* pos   = (const float*)d_in[1];
  const float* w1    = (const float*)d_in[2];
  const float* b1    = (const float*)d_in[3];
  const float* w2    = (const float*)d_in[4];
  const float* b2    = (const float*)d_in[5];
  const float* gamma = (const float*)d_in[6];
  const float* beta  = (const float*)d_in[7];
  float* out = (float*)d_out;

  char* ws = (char*)d_ws;
  ushort* w1b = (ushort*)(ws);                     // 2 MiB  (cast block start)
  ushort* w2b = (ushort*)(ws + (2u << 20));        // 2 MiB
  ushort* a1b = (ushort*)(ws + (4u << 20));        // 3 MiB: [eng;pos] bf16
  float*  xw1 = (float*)(ws + (7u << 20));         // 6 MiB: 1536x1024 f32
  ushort* hb  = (ushort*)(ws + (13u << 20));       // 64 MiB: 32768x1024 bf16

  // 1) fused casts to bf16 (w1|w2|eng|pos contiguous at ws base)
  cast_all_kernel<<<3584, 256, 0, stream>>>(w1, w2, eng, pos, w1b);

  // 2) GEMM1: xw1 = [engrams; pos] @ W1^T, +b1 folded into pos-rows
  gemm_bt<<<(A1_ROWS / 128) * (D_DIM / 128), 256, 0, stream>>>(a1b, w1b, xw1,
                                                               A1_ROWS, D_DIM, D_DIM,
                                                               b1, NE_ROWS);

  // 3) h = gelu(xw1_e + xw1_p) -> bf16   (b1 already folded)
  gelu_kernel<<<NROWS, 256, 0, stream>>>(xw1, hb);

  // 4) GEMM2: y(bf16) = h @ W2^T; 4-buffer ring, depth-3, 1 barrier/step
  gemm2_128<<<2048, 256, 0, stream>>>(hb, w2b, (ushort*)out);

  // 5) LayerNorm epilogue (exact fp32 residual recompute)
  ln_kernel<<<NROWS, 256, 0, stream>>>(eng, pos, b2, gamma, beta, out);
}

// Round 11
// 173.501 us; speedup vs baseline: 1.3779x; 1.0257x over previous
//
#include <hip/hip_runtime.h>
#include <hip/hip_bf16.h>
#include <math.h>

#define D_DIM 1024
#define NROWS 32768      // 4*16*512
#define NE_ROWS 1024     // 4*16*16 unique engram rows
#define A1_ROWS 1536     // engram rows + 512 pos rows
#define NT2 32           // GEMM2 K-steps of 32

typedef __attribute__((ext_vector_type(8))) short bf16x8;
typedef __attribute__((ext_vector_type(4))) float f32x4;

static __device__ __forceinline__ ushort f2bf(float f) {
  union { float f; unsigned u; } un; un.f = f;
  unsigned u = un.u;
  unsigned r = u + 0x7fffu + ((u >> 16) & 1u);
  return (ushort)(r >> 16);
}
static __device__ __forceinline__ float bf2f(ushort h) {
  union { unsigned u; float f; } un; un.u = ((unsigned)h) << 16;
  return un.f;
}
static __device__ __forceinline__ float gelu_exact(float v) {
  return 0.5f * v * (1.0f + erff(v * 0.70710678118654752f));
}

// ---- fused cast fp32 -> bf16 of w1|w2|eng|pos into contiguous ws region ----
__global__ void cast_all_kernel(const float* __restrict__ w1, const float* __restrict__ w2,
                                const float* __restrict__ eng, const float* __restrict__ pos,
                                ushort* __restrict__ dst) {
  int i = blockIdx.x * blockDim.x + threadIdx.x;   // float4 units, 0..917503
  float4 v;
  if (i < 262144) v = ((const float4*)w1)[i];
  else if (i < 524288) v = ((const float4*)w2)[i - 262144];
  else if (i < 786432) v = ((const float4*)eng)[i - 524288];
  else v = ((const float4*)pos)[i - 786432];
  ushort4 o;
  o.x = f2bf(v.x); o.y = f2bf(v.y); o.z = f2bf(v.z); o.w = f2bf(v.w);
  ((ushort4*)dst)[i] = o;
}

// ---- pack W2 (bf16, row-major) into fragment-linear order for gemm2 ----
// BP entry id = (((nt*2+wc)*32 + kt)*4 + n)*64 + l  holds
// W2[nt*128 + wc*64 + n*16 + (l&15)][kt*32 + (l>>4)*8 .. +8]
__global__ __launch_bounds__(256) void packB_kernel(const ushort* __restrict__ w2b,
                                                    ushort* __restrict__ pack) {
  int id = blockIdx.x * 256 + threadIdx.x;     // 0..131071
  int l = id & 63;
  int n = (id >> 6) & 3;
  int kt = (id >> 8) & 31;
  int wcnt = id >> 13;                         // nt*2+wc
  int c = (wcnt >> 1) * 128 + (wcnt & 1) * 64 + n * 16 + (l & 15);
  int k = kt * 32 + (l >> 4) * 8;
  bf16x8 v = *(const bf16x8*)(w2b + ((size_t)c << 10) + k);
  *(bf16x8*)(pack + ((size_t)id << 3)) = v;
}

// ---- 128x128 bf16 MFMA GEMM + row-ranged bias (b1 folded into pos rows) ----
__global__ __launch_bounds__(256) void gemm_bt(const ushort* __restrict__ A,
                                               const ushort* __restrict__ B,
                                               float* __restrict__ C,
                                               int M, int N, int K,
                                               const float* __restrict__ bias,
                                               int biasRow0) {
  __shared__ ushort sA[128 * 64];
  __shared__ ushort sB[128 * 64];

  int nwg = gridDim.x;
  int bid = blockIdx.x;
  if ((nwg & 7) == 0) {
    int cpx = nwg >> 3;
    bid = (bid & 7) * cpx + (bid >> 3);
  }
  int ntn = N >> 7;
  int mt = bid / ntn, nt = bid % ntn;
  int brow = mt << 7, bcol = nt << 7;

  int tid = threadIdx.x;
  int wv = tid >> 6, lane = tid & 63;
  int wm = (wv >> 1) << 6, wn = (wv & 1) << 6;
  int lr = lane & 15, lk = lane >> 4;
  int srow = lane >> 3;
  int scolsw = (((lane & 7) ^ ((lane >> 3) & 7)) << 3);

  f32x4 acc[4][4];
#pragma unroll
  for (int m = 0; m < 4; ++m)
#pragma unroll
    for (int n = 0; n < 4; ++n) acc[m][n] = (f32x4){0.f, 0.f, 0.f, 0.f};

  for (int k0 = 0; k0 < K; k0 += 64) {
    __syncthreads();
#pragma unroll
    for (int j = 0; j < 4; ++j) {
      int c = (wv << 2) + j;
      int row = (c << 3) + srow;
      const ushort* gA = A + (brow + row) * K + k0 + scolsw;
      const ushort* gB = B + (bcol + row) * K + k0 + scolsw;
      __builtin_amdgcn_global_load_lds(
          (const __attribute__((address_space(1))) unsigned int*)gA,
          (__attribute__((address_space(3))) unsigned int*)&sA[c << 9], 16, 0, 0);
      __builtin_amdgcn_global_load_lds(
          (const __attribute__((address_space(1))) unsigned int*)gB,
          (__attribute__((address_space(3))) unsigned int*)&sB[c << 9], 16, 0, 0);
    }
    __syncthreads();
#pragma unroll
    for (int kk = 0; kk < 2; ++kk) {
      int rdoff = (((kk << 2) | lk) ^ (lr & 7)) << 3;
      bf16x8 af[4], bfr[4];
#pragma unroll
      for (int m = 0; m < 4; ++m)
        af[m] = *(const bf16x8*)&sA[(wm + (m << 4) + lr) * 64 + rdoff];
#pragma unroll
      for (int n = 0; n < 4; ++n)
        bfr[n] = *(const bf16x8*)&sB[(wn + (n << 4) + lr) * 64 + rdoff];
#pragma unroll
      for (int m = 0; m < 4; ++m)
#pragma unroll
        for (int n = 0; n < 4; ++n)
          acc[m][n] = __builtin_amdgcn_mfma_f32_16x16x32_bf16(af[m], bfr[n], acc[m][n], 0, 0, 0);
    }
  }

#pragma unroll
  for (int m = 0; m < 4; ++m)
#pragma unroll
    for (int n = 0; n < 4; ++n)
#pragma unroll
      for (int i = 0; i < 4; ++i) {
        int row = brow + wm + (m << 4) + (lk << 2) + i;
        int col = bcol + wn + (n << 4) + lr;
        float v = acc[m][n][i];
        if (row >= biasRow0) v += bias[col];
        C[(long)row * N + col] = v;
      }
}

// ---- h = gelu_exact(xw1_e[er] + xw1_p[w]) -> bf16 (b1 already in pos rows) ----
__global__ __launch_bounds__(256) void gelu_kernel(const float* __restrict__ xw1,
                                                   ushort* __restrict__ h) {
  int r = blockIdx.x;
  int t = threadIdx.x;
  int bn = r >> 9;
  int w = r & 511;
  int er = bn * 16 + (w >> 5);
  float4 e = ((const float4*)(xw1 + er * D_DIM))[t];
  float4 p = ((const float4*)(xw1 + (NE_ROWS + w) * D_DIM))[t];
  ushort4 o;
  o.x = f2bf(gelu_exact(e.x + p.x));
  o.y = f2bf(gelu_exact(e.y + p.y));
  o.z = f2bf(gelu_exact(e.z + p.z));
  o.w = f2bf(gelu_exact(e.w + p.w));
  ((ushort4*)(h + (long)r * D_DIM))[t] = o;
}

// ---- GEMM2: 128x128 tile, 4 waves; A via LDS (16 KiB), B from packed L2 ----
// Y(bf16) = h @ W2^T, interleaved: ushort at Y + row*2048 + col.
// B-fragments are coalesced 1KB loads from fragment-linear BP (no LDS, no gather).
// Ledger: prologue {A0(2),B0(4),A1(2); vmcnt(2)}. Step t: +B(t+1)(4) at top;
// BAR; +A(t+2)(2); vmcnt(2) certifies A(t+1)+B(t+1); BAR.
// A swizzle: phys 16B-slot s at row r holds logical s^((r>>1)&3).
__global__ __launch_bounds__(256, 4) void gemm2_128(const ushort* __restrict__ A,
                                                    const ushort* __restrict__ BP,
                                                    ushort* __restrict__ Y) {
  __shared__ ushort sA[2][4096];
  const int K = 1024;

  // XCD map: all 8 N-tiles of an M-panel stay on one XCD (A L2-reuse)
  int bid = blockIdx.x;                // 2048 blocks
  int x = bid & 7, jj = bid >> 3;
  int mt = (x << 5) + (jj >> 3);       // 0..255
  int nt = jj & 7;                     // 0..7
  long brow = (long)mt << 7;
  int bcol = nt << 7;

  int tid = threadIdx.x;
  int wv = tid >> 6, l = tid & 63;
  int wr = wv >> 1, wc = wv & 1;       // 2x2 wave grid; wave tile 64x64
  int lr = l & 15, lk = l >> 4;

  // A staging: instr j2 covers rows [j2*64, j2*64+64): row = j2*64 + wv*16 + (l>>2)
  int srow0 = (wv << 4) + (l >> 2);
  int slog = (((l & 3) ^ ((l >> 3) & 3)) << 3);
  const ushort* aS = A + (brow + srow0) * (long)K + slog;

  // A fragment read offsets (swizzled)
  int rdswz = (lk ^ ((lr >> 1) & 3)) << 3;
  int aO = (((wr << 6) + lr) << 5) + rdswz;   // + m<<9

  // packed-B base for this (nt, wc); fragment (kt,n) at + ((kt*4+n)*64 + l)*8
  const ushort* bP = BP + (((size_t)((nt << 1) | wc)) << 16) + (l << 3);

  f32x4 acc[4][4];
#pragma unroll
  for (int m = 0; m < 4; ++m)
#pragma unroll
    for (int n = 0; n < 4; ++n) acc[m][n] = (f32x4){0.f, 0.f, 0.f, 0.f};

#define STG(kt) do {                                                                 \
    int p_ = (kt) & 1; int ko_ = (kt) << 5;                                          \
    _Pragma("unroll")                                                                \
    for (int j2 = 0; j2 < 2; ++j2) {                                                 \
      __builtin_amdgcn_global_load_lds(                                              \
        (const __attribute__((address_space(1))) unsigned int*)(aS + ko_ + (long)(j2 << 6) * K), \
        (__attribute__((address_space(3))) unsigned int*)&sA[p_][(j2 << 11) + (wv << 9)], 16, 0, 0); \
    } } while (0)

#define LDB(BUF, kt) do {                                                            \
    _Pragma("unroll")                                                                \
    for (int n = 0; n < 4; ++n)                                                      \
      BUF[n] = *(const bf16x8*)(bP + ((((kt) << 2) | n) << 9));                      \
    __builtin_amdgcn_sched_barrier(0);                                               \
  } while (0)

#define BAR asm volatile("s_barrier" ::: "memory")

  bf16x8 bA[4], bB[4];

  // prologue: FIFO = A0(2), B0(4), A1(2); vmcnt(2) certifies A0+B0, leaves A1.
  STG(0);
  __builtin_amdgcn_sched_barrier(0);
  LDB(bA, 0);
  STG(1);
  asm volatile("s_waitcnt vmcnt(2)" ::: "memory");
  BAR;

  // STEP(t, BU, BL): uses BU=B(t), prefetches B(t+1) into BL at top of step.
#define STEP(t, BU, BL) do {                                                         \
    if ((t) + 1 < NT2) LDB(BL, (t) + 1);        /* full step of flight to land */    \
    bf16x8 af[4];                                                                    \
    _Pragma("unroll")                                                                \
    for (int m = 0; m < 4; ++m) af[m] = *(const bf16x8*)&sA[(t) & 1][aO + (m << 9)]; \
    __builtin_amdgcn_s_setprio(1);                                                   \
    _Pragma("unroll")                                                                \
    for (int m = 0; m < 4; ++m)                                                      \
      _Pragma("unroll")                                                              \
      for (int n = 0; n < 4; ++n)                                                    \
        acc[m][n] = __builtin_amdgcn_mfma_f32_16x16x32_bf16(af[m], BU[n], acc[m][n], 0, 0, 0); \
    __builtin_amdgcn_s_setprio(0);                                                   \
    if ((t) < NT2 - 1) {                                                             \
      BAR;                                       /* all waves done reading sA[t&1] */ \
      if ((t) + 2 < NT2) {                                                           \
        STG((t) + 2);                                                                \
        asm volatile("s_waitcnt vmcnt(2)" ::: "memory");  /* certify A(t+1)+B(t+1) */ \
      } else {                                                                       \
        asm volatile("s_waitcnt vmcnt(0)" ::: "memory");  /* tail drain */           \
      }                                                                              \
      BAR;                                                                           \
    }                                                                                \
  } while (0)

  for (int t = 0; t < NT2; t += 2) {
    STEP(t, bA, bB);
    STEP(t + 1, bB, bA);
  }
#undef STEP
#undef STG
#undef LDB
#undef BAR

  // epilogue: bf16 y into interleaved out rows (first 1024 ushorts of 4KB row)
#pragma unroll
  for (int m = 0; m < 4; ++m)
#pragma unroll
    for (int n = 0; n < 4; ++n) {
      int col = bcol + (wc << 6) + (n << 4) + lr;
#pragma unroll
      for (int i = 0; i < 4; ++i) {
        long row = brow + (wr << 6) + (m << 4) + (lk << 2) + i;
        Y[(row << 11) + col] = f2bf(acc[m][n][i]);
      }
    }
}

// ---- out = LayerNorm((eng+pos) + y + b2); y read bf16-interleaved from out ----
__global__ __launch_bounds__(256) void ln_kernel(const float* __restrict__ eng,
                                                 const float* __restrict__ pos,
                                                 const float* __restrict__ b2,
                                                 const float* __restrict__ gamma,
                                                 const float* __restrict__ beta,
                                                 float* __restrict__ out) {
  __shared__ float red[8];
  int r = blockIdx.x;
  int t = threadIdx.x;
  int bn = r >> 9, w = r & 511;
  int er = bn * 16 + (w >> 5);
  float4 xe = ((const float4*)(eng + er * D_DIM))[t];
  float4 xp = ((const float4*)(pos + w * D_DIM))[t];
  ushort4 yv = ((const ushort4*)((const ushort*)out + ((size_t)r << 11)))[t];
  float4 bb = ((const float4*)b2)[t];
  float v0 = xe.x + xp.x + bf2f(yv.x) + bb.x;
  float v1 = xe.y + xp.y + bf2f(yv.y) + bb.y;
  float v2 = xe.z + xp.z + bf2f(yv.z) + bb.z;
  float v3 = xe.w + xp.w + bf2f(yv.w) + bb.w;
  float s  = v0 + v1 + v2 + v3;
  float sq = v0 * v0 + v1 * v1 + v2 * v2 + v3 * v3;
  int lane = t & 63, wv = t >> 6;
#pragma unroll
  for (int off = 32; off > 0; off >>= 1) {
    s  += __shfl_down(s, off);
    sq += __shfl_down(sq, off);
  }
  if (lane == 0) { red[wv] = s; red[4 + wv] = sq; }
  __syncthreads();
  float S  = red[0] + red[1] + red[2] + red[3];
  float SQ = red[4] + red[5] + red[6] + red[7];
  float mu = S * (1.0f / 1024.0f);
  float var = SQ * (1.0f / 1024.0f) - mu * mu;
  float rs = rsqrtf(var + 1e-5f);
  float4 g = ((const float4*)gamma)[t];
  float4 bt = ((const float4*)beta)[t];
  float4 o;
  o.x = (v0 - mu) * rs * g.x + bt.x;
  o.y = (v1 - mu) * rs * g.y + bt.y;
  o.z = (v2 - mu) * rs * g.z + bt.z;
  o.w = (v3 - mu) * rs * g.w + bt.w;
  ((float4*)(out + ((size_t)r << 10)))[t] = o;
}

extern "C" void kernel_launch(void* const* d_in, const int* in_sizes, int n_in,
                              void* d_out, int out_size, void* d_ws, size_t ws_size,
                              hipStream_t stream) {
  const float* eng   = (const float*)d_in[0];
  const float* pos   = (const float*)d_in[1];
  const float* w1    = (const float*)d_in[2];
  const float* b1    = (const float*)d_in[3];
  const float* w2    = (const float*)d_in[4];
  const float* b2    = (const float*)d_in[5];
  const float* gamma = (const float*)d_in[6];
  const float* beta  = (const float*)d_in[7];
  float* out = (float*)d_out;

  char* ws = (char*)d_ws;
  ushort* w1b = (ushort*)(ws);                     // 2 MiB  (cast block start)
  ushort* w2b = (ushort*)(ws + (2u << 20));        // 2 MiB
  ushort* a1b = (ushort*)(ws + (4u << 20));        // 3 MiB: [eng;pos] bf16
  float*  xw1 = (float*)(ws + (7u << 20));         // 6 MiB: 1536x1024 f32
  ushort* hb  = (ushort*)(ws + (13u << 20));       // 64 MiB: 32768x1024 bf16
  ushort* bpk = (ushort*)(ws + (77u << 20));       // 2 MiB: packed W2 fragments

  // 1) fused casts to bf16 (w1|w2|eng|pos contiguous at ws base)
  cast_all_kernel<<<3584, 256, 0, stream>>>(w1, w2, eng, pos, w1b);

  // 1b) pack W2 into fragment-linear order for gemm2's direct-B path
  packB_kernel<<<512, 256, 0, stream>>>(w2b, bpk);

  // 2) GEMM1: xw1 = [engrams; pos] @ W1^T, +b1 folded into pos-rows
  gemm_bt<<<(A1_ROWS / 128) * (D_DIM / 128), 256, 0, stream>>>(a1b, w1b, xw1,
                                                               A1_ROWS, D_DIM, D_DIM,
                                                               b1, NE_ROWS);

  // 3) h = gelu(xw1_e + xw1_p) -> bf16   (b1 already folded)
  gelu_kernel<<<NROWS, 256, 0, stream>>>(xw1, hb);

  // 4) GEMM2: y(bf16) = h @ W2^T; A via LDS, B via packed coalesced L2 loads
  gemm2_128<<<2048, 256, 0, stream>>>(hb, bpk, (ushort*)out);

  // 5) LayerNorm epilogue (exact fp32 residual recompute)
  ln_kernel<<<NROWS, 256, 0, stream>>>(eng, pos, b2, gamma, beta, out);
}